// Round 1
// baseline (629.695 us; speedup 1.0000x reference)
//
#include <hip/hip_runtime.h>
#include <hip/hip_bf16.h>
#include <cstdint>

typedef __attribute__((ext_vector_type(8))) short short8;
typedef __attribute__((ext_vector_type(4))) float floatx4;

#define HIDDEN 128
#define NOUT 256

// ---------------------------------------------------------------------------
// One-time weight convert + transpose to bf16.
// WdT[n][k] = W_down[k][n] (256x128); WsT[l][n][k] = Ws[l][k][n] (3x256x256)
// ---------------------------------------------------------------------------
__global__ __launch_bounds__(256) void prep_weights(
    const float* __restrict__ Wd, const float* __restrict__ Ws,
    __hip_bfloat16* __restrict__ WdT, __hip_bfloat16* __restrict__ WsT)
{
    int tid = blockIdx.x * 256 + threadIdx.x;
    if (tid < 256 * 128) {
        int n = tid >> 7, k = tid & 127;
        WdT[tid] = __float2bfloat16(Wd[k * 256 + n]);
    }
    int tid2 = tid - 256 * 128;
    if (tid2 >= 0 && tid2 < 3 * 256 * 256) {
        int l = tid2 >> 16;
        int rem = tid2 & 65535;
        int n = rem >> 8, k = rem & 255;
        WsT[tid2] = __float2bfloat16(Ws[l * 65536 + k * 256 + n]);
    }
}

// ---------------------------------------------------------------------------
// CSR build: histogram -> 3-kernel parallel exclusive scan -> stable fill.
// ---------------------------------------------------------------------------
__global__ __launch_bounds__(256) void hist_k(
    const int* __restrict__ idx, int* __restrict__ cnt, int E)
{
    int e = blockIdx.x * 256 + threadIdx.x;
    if (e < E) atomicAdd(&cnt[idx[e]], 1);
}

__global__ __launch_bounds__(256) void scan_blocksum_k(
    const int* __restrict__ cnt, int* __restrict__ blocksum, int M)
{
    int base = blockIdx.x * 1024;
    int t = threadIdx.x;
    int s = 0;
#pragma unroll
    for (int j = 0; j < 4; ++j) {
        int p = base + t * 4 + j;
        if (p < M) s += cnt[p];
    }
#pragma unroll
    for (int d = 32; d > 0; d >>= 1) s += __shfl_down(s, d);
    __shared__ int wsum[4];
    if ((t & 63) == 0) wsum[t >> 6] = s;
    __syncthreads();
    if (t == 0) blocksum[blockIdx.x] = wsum[0] + wsum[1] + wsum[2] + wsum[3];
}

__global__ __launch_bounds__(64) void scan_base_k(
    const int* __restrict__ blocksum, int* __restrict__ blockbase,
    int* __restrict__ offsets, int nb, int M)
{
    int lane = threadIdx.x;
    int carry = 0;
    for (int base = 0; base < nb; base += 64) {
        int v = (base + lane < nb) ? blocksum[base + lane] : 0;
        int incl = v;
#pragma unroll
        for (int d = 1; d < 64; d <<= 1) {
            int u = __shfl_up(incl, d);
            if (lane >= d) incl += u;
        }
        if (base + lane < nb) blockbase[base + lane] = carry + incl - v;
        carry += __shfl(incl, 63);
    }
    if (lane == 0) offsets[M] = carry;
}

__global__ __launch_bounds__(256) void scan_offsets_k(
    const int* __restrict__ cnt, const int* __restrict__ blockbase,
    int* __restrict__ offsets, int* __restrict__ cursor, int M)
{
    int base = blockIdx.x * 1024;
    int t = threadIdx.x, lane = t & 63, wv = t >> 6;
    int v[4];
    int s = 0;
#pragma unroll
    for (int j = 0; j < 4; ++j) {
        int p = base + t * 4 + j;
        v[j] = (p < M) ? cnt[p] : 0;
        s += v[j];
    }
    int incl = s;
#pragma unroll
    for (int d = 1; d < 64; d <<= 1) {
        int u = __shfl_up(incl, d);
        if (lane >= d) incl += u;
    }
    __shared__ int wtot[4];
    if (lane == 63) wtot[wv] = incl;
    __syncthreads();
    int wbase = 0;
    for (int j = 0; j < wv; ++j) wbase += wtot[j];
    int start = blockbase[blockIdx.x] + wbase + incl - s;
#pragma unroll
    for (int j = 0; j < 4; ++j) {
        int p = base + t * 4 + j;
        if (p < M) { offsets[p] = start; cursor[p] = start; }
        start += v[j];
    }
}

__global__ __launch_bounds__(256) void fill_k(
    const int* __restrict__ idx, int* __restrict__ cursor,
    int* __restrict__ edge_ids, int E)
{
    int e = blockIdx.x * 256 + threadIdx.x;
    if (e < E) {
        int pos = atomicAdd(&cursor[idx[e]], 1);
        edge_ids[pos] = e;
    }
}

// ---------------------------------------------------------------------------
// Gather v2: one wave per node, lane owns 2 hidden channels.
// Change vs v1: edge ids for the node are fetched in ONE coalesced load per
// 64-edge chunk (lane p+l), then broadcast via v_readlane (SALU, no memory
// op on the critical path). Inner loop unrolled x4 so 4 independent x-row
// loads are in flight per wave (was 1 -> latency-serialized).
// hacc is written as bf16 (identical numerics: MLP converted to bf16 anyway),
// halving hacc traffic.
// ---------------------------------------------------------------------------
__global__ __launch_bounds__(256) void gather_k(
    const float* __restrict__ x, const float* __restrict__ rbf,
    const float* __restrict__ Wrbf, const int* __restrict__ offsets,
    const int* __restrict__ edge_ids, __hip_bfloat16* __restrict__ hacc, int M)
{
    int t = threadIdx.x;
    int wave = t >> 6, lane = t & 63;
    int n = blockIdx.x * 4 + wave;
    if (n >= M) return;

    int c0 = lane * 2;
    float w0[6], w1[6];
#pragma unroll
    for (int r = 0; r < 6; ++r) {
        w0[r] = Wrbf[r * HIDDEN + c0];
        w1[r] = Wrbf[r * HIDDEN + c0 + 1];
    }

    int s = offsets[n], eend = offsets[n + 1];
    float a0 = 0.f, a1 = 0.f;

    for (int p = s; p < eend; p += 64) {
        int nb = eend - p;
        if (nb > 64) nb = 64;
        // one coalesced load of up to 64 edge ids for this chunk
        int eid = (p + lane < eend) ? edge_ids[p + lane] : 0;

        int j = 0;
        for (; j + 4 <= nb; j += 4) {
#pragma unroll
            for (int u = 0; u < 4; ++u) {
                int e = __builtin_amdgcn_readlane(eid, j + u);   // uniform -> SGPR
                const float* rb = rbf + (long)e * 6;             // uniform -> s_load
                float2 xv = *(const float2*)&x[(long)e * HIDDEN + c0];
                float p0 = 0.f, p1 = 0.f;
#pragma unroll
                for (int r = 0; r < 6; ++r) {
                    float rv = rb[r];
                    p0 += rv * w0[r];
                    p1 += rv * w1[r];
                }
                a0 += p0 * xv.x;
                a1 += p1 * xv.y;
            }
        }
        for (; j < nb; ++j) {
            int e = __builtin_amdgcn_readlane(eid, j);
            const float* rb = rbf + (long)e * 6;
            float2 xv = *(const float2*)&x[(long)e * HIDDEN + c0];
            float p0 = 0.f, p1 = 0.f;
#pragma unroll
            for (int r = 0; r < 6; ++r) {
                float rv = rb[r];
                p0 += rv * w0[r];
                p1 += rv * w1[r];
            }
            a0 += p0 * xv.x;
            a1 += p1 * xv.y;
        }
    }

    __hip_bfloat162 pk;
    pk.x = __float2bfloat16(a0);
    pk.y = __float2bfloat16(a1);
    *(__hip_bfloat162*)&hacc[(long)n * HIDDEN + c0] = pk;
}

// ---------------------------------------------------------------------------
// Fused MLP v2: down-proj + 3 SiLU layers in ONE kernel. Block = 64 rows.
// Change vs v1: B operand comes straight from global (L2-hot: 512 KB total
// weights, re-read by all 782 blocks) into registers with a 1-deep explicit
// prefetch -> compiler emits counted vmcnt, no vmcnt(0) stalls. The Wl LDS
// buffer and its 2-barriers-per-slab are GONE: barriers are now only the 2
// per layer that fence the Al rewrite (28 -> 8 per block).
// LDS = Al only (64x264 bf16 = 33.8 KB) -> 3+ blocks/CU (was 2).
// Layouts (HW-verified in prior session): A[m=lane&15][k=(lane>>4)*8+j];
//                                         C/D col=lane&15, row=(lane>>4)*4+reg.
// ---------------------------------------------------------------------------
__global__ __launch_bounds__(256, 3) void mlp_fused(
    const __hip_bfloat16* __restrict__ hacc, const __hip_bfloat16* __restrict__ WdT,
    const __hip_bfloat16* __restrict__ WsT, const float* __restrict__ bs,
    float* __restrict__ out, int M)
{
    __shared__ __hip_bfloat16 Al[64][264];   // 256 cols + 8 pad

    int t = threadIdx.x;
    int lane = t & 63, w = t >> 6;
    int q = lane >> 4, r16 = lane & 15;
    int m0 = blockIdx.x * 64;

    // stage hacc tile (64 x 128 bf16) -> Al : 1024 16B chunks, 4 per thread
#pragma unroll
    for (int it = 0; it < 4; ++it) {
        int idx = it * 256 + t;
        int row = idx >> 4;              // 16 chunks / row
        int col = (idx & 15) * 8;
        int gr = m0 + row; if (gr >= M) gr = M - 1;
        *(short8*)&Al[row][col] = *(const short8*)&hacc[(long)gr * HIDDEN + col];
    }
    __syncthreads();

    for (int layer = 0; layer < 4; ++layer) {
        const int K = (layer == 0) ? 128 : 256;
        const __hip_bfloat16* BT = (layer == 0) ? WdT : WsT + (layer - 1) * 65536;
        const __hip_bfloat16* Brow = BT + (long)(w * 64 + r16) * K;  // + nt*16*K per n-tile

        floatx4 acc[4][4] = {};
        short8 bcur[4], bnxt[4];
#pragma unroll
        for (int nt = 0; nt < 4; ++nt)
            bcur[nt] = *(const short8*)&Brow[(long)nt * 16 * K + q * 8];

        for (int kk = 0; kk < K; kk += 32) {
            short8 af[4];
#pragma unroll
            for (int mt = 0; mt < 4; ++mt)
                af[mt] = *(const short8*)&Al[mt * 16 + r16][kk + q * 8];
            int kn = kk + 32;
            if (kn < K) {
#pragma unroll
                for (int nt = 0; nt < 4; ++nt)
                    bnxt[nt] = *(const short8*)&Brow[(long)nt * 16 * K + kn + q * 8];
            }
#pragma unroll
            for (int mt = 0; mt < 4; ++mt)
#pragma unroll
                for (int nt = 0; nt < 4; ++nt)
                    acc[mt][nt] = __builtin_amdgcn_mfma_f32_16x16x32_bf16(
                        af[mt], bcur[nt], acc[mt][nt], 0, 0, 0);
#pragma unroll
            for (int nt = 0; nt < 4; ++nt) bcur[nt] = bnxt[nt];
        }

        if (layer < 3) {
            __syncthreads();   // all Al reads done before rewrite
            const float* bias = (layer == 0) ? nullptr : bs + (layer - 1) * 256;
#pragma unroll
            for (int mt = 0; mt < 4; ++mt) {
#pragma unroll
                for (int rr = 0; rr < 4; ++rr) {
                    int row = mt * 16 + q * 4 + rr;
#pragma unroll
                    for (int nt = 0; nt < 4; ++nt) {
                        int col = w * 64 + nt * 16 + r16;
                        float v = acc[mt][nt][rr];
                        if (layer > 0) { v += bias[col]; v = v / (1.f + __expf(-v)); }
                        Al[row][col] = __float2bfloat16(v);
                    }
                }
            }
            __syncthreads();   // Al rewrite visible before next layer's reads
        } else {
            const float* bias = bs + 2 * 256;
#pragma unroll
            for (int mt = 0; mt < 4; ++mt) {
#pragma unroll
                for (int rr = 0; rr < 4; ++rr) {
                    int row = m0 + mt * 16 + q * 4 + rr;
                    if (row < M) {
#pragma unroll
                        for (int nt = 0; nt < 4; ++nt) {
                            int col = w * 64 + nt * 16 + r16;
                            float v = acc[mt][nt][rr] + bias[col];
                            v = v / (1.f + __expf(-v));
                            out[(long)row * NOUT + col] = v;
                        }
                    }
                }
            }
        }
    }
}

// ---------------------------------------------------------------------------
extern "C" void kernel_launch(void* const* d_in, const int* in_sizes, int n_in,
                              void* d_out, int out_size, void* d_ws, size_t ws_size,
                              hipStream_t stream)
{
    const float* x    = (const float*)d_in[0];
    const float* rbf  = (const float*)d_in[1];
    const int*   idx  = (const int*)d_in[2];
    const float* Wrbf = (const float*)d_in[3];
    const float* Wd   = (const float*)d_in[4];
    const float* Ws   = (const float*)d_in[5];
    const float* bs   = (const float*)d_in[6];

    int E = in_sizes[0] / HIDDEN;
    int M = out_size / NOUT;         // num_nodes
    int nb = (M + 1023) / 1024;

    char* ws = (char*)d_ws;
    __hip_bfloat16* hacc = (__hip_bfloat16*)ws;                  // M*128 bf16 (reserve fp32 size)
    size_t off = (size_t)M * HIDDEN * sizeof(float);
    __hip_bfloat16* WdT = (__hip_bfloat16*)(ws + off); off += 256 * 128 * 2;
    __hip_bfloat16* WsT = (__hip_bfloat16*)(ws + off); off += 3 * 256 * 256 * 2;
    int* cnt       = (int*)(ws + off); off += (size_t)M * 4;
    int* offsets   = (int*)(ws + off); off += (size_t)(M + 1) * 4;
    int* cursor    = (int*)(ws + off); off += (size_t)M * 4;
    int* edge_ids  = (int*)(ws + off); off += (size_t)E * 4;
    int* blocksum  = (int*)(ws + off); off += (size_t)nb * 4;
    int* blockbase = (int*)(ws + off); off += (size_t)nb * 4;

    hipMemsetAsync(cnt, 0, (size_t)M * sizeof(int), stream);
    prep_weights<<<(256 * 128 + 3 * 256 * 256 + 255) / 256, 256, 0, stream>>>(Wd, Ws, WdT, WsT);
    hist_k<<<(E + 255) / 256, 256, 0, stream>>>(idx, cnt, E);
    scan_blocksum_k<<<nb, 256, 0, stream>>>(cnt, blocksum, M);
    scan_base_k<<<1, 64, 0, stream>>>(blocksum, blockbase, offsets, nb, M);
    scan_offsets_k<<<nb, 256, 0, stream>>>(cnt, blockbase, offsets, cursor, M);
    fill_k<<<(E + 255) / 256, 256, 0, stream>>>(idx, cursor, edge_ids, E);
    gather_k<<<(M + 3) / 4, 256, 0, stream>>>(x, rbf, Wrbf, offsets, edge_ids, hacc, M);
    mlp_fused<<<(M + 63) / 64, 256, 0, stream>>>(hacc, WdT, WsT, bs, (float*)d_out, M);
}